// Round 3
// baseline (509.877 us; speedup 1.0000x reference)
//
#include <hip/hip_runtime.h>

// confidence_maps: (8,6,4,512,512) f32; warp_masks: (8,1,512,512) f32;
// gauss_kernel: (1,1,5,5) f32.
// Output: mask (48,1,512,512) f32 + rate scalar = 12,582,913 floats.
//
// Validated invariants (rounds 1-2, absmax 0.0):
//  - rate == 0.5 exactly; ego rows (l==0) all-ones, no compute, excluded from rate.
//  - max_c(sigmoid) == sigmoid(max_c); f64 pipeline matches np ref ordering.
//
// Round-3 changes (round 2 post-mortem: launch_bounds(512,8) -> VGPR=32 ->
// ~190 MB scratch spill traffic, kernel became spill-bound):
//  - u16 keys (21 MB instead of 42 MB f64/u32 array).
//  - 4096-bin histogram fused in compute -> single-level selection; hist2 and
//    scan2 passes deleted (~84 MB traffic removed). Cutoff bin ~510 cand/row.
//  - tile 64x32, LDS 36 KB -> 4 blocks/CU, launch_bounds(256,4) (no spill).

#define NROWSEL 40
#define NPIX    262144
#define KSEL    131072u
#define CAND_CAP 4096

// ---- workspace layout (bytes) ----
#define OFF_KEY  0ull                  // 40*262144 u16 = 20,971,520
#define OFF_H1   20971520ull           // 40*4096 u32   =    655,360
#define OFF_ST   21626880ull           // 40*4 int      =        640
#define OFF_CC   21627520ull           // 40 u32        =        160
#define OFF_CI   21627680ull           // 40*4096 int   =    655,360
#define META_BYTES 656160ull           // zero H1 + ST + CC

__device__ __forceinline__ unsigned qkey(double v) {
  double t = v * 4294967296.0;
  t = fmax(t, 0.0);
  t = fmin(t, 4294967295.0);
  return (unsigned)t;
}

// m = sigmoid(max_c conf) * warp, f64. Shared by compute & finalize so the
// recomputation in finalize is BIT-IDENTICAL.
__device__ __forceinline__ double m_val(const float* __restrict__ confr,
                                        const float* __restrict__ warpr,
                                        int gy, int gx) {
  if (gy < 0 || gy >= 512 || gx < 0 || gx >= 512) return 0.0;
  int off = gy * 512 + gx;
  float x0 = confr[off];
  float x1 = confr[NPIX + off];
  float x2 = confr[2 * NPIX + off];
  float x3 = confr[3 * NPIX + off];
  float mx = fmaxf(fmaxf(x0, x1), fmaxf(x2, x3));
  double s = 1.0 / (1.0 + exp(-(double)mx));
  return s * (double)warpr[off];
}

__global__ void ego_fill_kernel(float* __restrict__ out) {
  int i = blockIdx.x * 256 + threadIdx.x;   // 524288 float4 units
  int b = i >> 16;
  int o4 = i & 65535;
  float4* p = (float4*)(out + (size_t)b * 6u * NPIX) + o4;
  *p = make_float4(1.f, 1.f, 1.f, 1.f);
}

// Fused: f64 m halo tile (36x68) in LDS, 25-tap f64 conv (fixed fma chain),
// u16 key store, 4096-bin LDS histogram of key bits [31:20].
__global__ __launch_bounds__(256, 4) void compute_kernel(
    const float* __restrict__ conf, const float* __restrict__ warp,
    const float* __restrict__ gk, unsigned short* __restrict__ keys,
    unsigned* __restrict__ hist1) {
  const int blk = blockIdx.x;        // 40 * 128
  const int j = blk >> 7;            // row 0..39
  const int tile = blk & 127;        // 16 (y) x 8 (x) tiles of 32x64
  const int ty0 = (tile >> 3) << 5;
  const int tx0 = (tile & 7) << 6;
  const int b = j / 5;
  const int l = j % 5 + 1;
  const int rowg = b * 6 + l;
  const float* confr = conf + (size_t)rowg * 4u * NPIX;
  const float* warpr = warp + (size_t)b * NPIX;

  __shared__ double mt[36][68];      // 19584 B
  __shared__ double g[25];
  __shared__ unsigned lh[4096];      // 16384 B  => ~36.2 KB total
  const int tid = threadIdx.x;
  if (tid < 25) g[tid] = (double)gk[tid];
  for (int i = tid; i < 4096; i += 256) lh[i] = 0u;

  for (int i = tid; i < 36 * 68; i += 256) {
    int hy = i / 68, hx = i % 68;
    mt[hy][hx] = m_val(confr, warpr, ty0 + hy - 2, tx0 + hx - 2);
  }
  __syncthreads();

  const int txl = tid & 63;
  const int tyl = tid >> 6;          // 0..3
  unsigned short* keyrow = keys + (size_t)j * NPIX;
  for (int rr = 0; rr < 8; ++rr) {
    int yy = tyl + (rr << 2);        // 0..31
    double acc = 0.0;
#pragma unroll
    for (int dy = 0; dy < 5; ++dy)
#pragma unroll
      for (int dx = 0; dx < 5; ++dx)
        acc = fma(g[dy * 5 + dx], mt[yy + dy][txl + dx], acc);
    unsigned k = qkey(acc);
    keyrow[(ty0 + yy) * 512 + (tx0 + txl)] = (unsigned short)(k >> 16);
    atomicAdd(&lh[k >> 20], 1u);
  }
  __syncthreads();
  unsigned* h1 = hist1 + j * 4096;
  for (int i = tid; i < 4096; i += 256)
    if (lh[i]) atomicAdd(&h1[i], lh[i]);
}

// Find cutoff bin b1 (descending over 4096 bins); A1 = count strictly above.
__global__ void scan1_kernel(const unsigned* __restrict__ hist1,
                             int* __restrict__ st) {
  int j = blockIdx.x;
  const unsigned* h = hist1 + j * 4096;
  __shared__ unsigned cs[256];
  int tid = threadIdx.x;
  unsigned s = 0;
  for (int k = 0; k < 16; ++k) s += h[tid * 16 + k];
  cs[tid] = s;
  __syncthreads();
  if (tid == 0) {
    unsigned cum = 0; int b1 = 0; unsigned A1 = 0;
    for (int c = 255; c >= 0; --c) {
      if (cum + cs[c] >= KSEL) {
        unsigned cc2 = cum;
        for (int k = 15; k >= 0; --k) {
          unsigned hv = h[c * 16 + k];
          if (cc2 + hv >= KSEL) { b1 = c * 16 + k; A1 = cc2; break; }
          cc2 += hv;
        }
        break;
      }
      cum += cs[c];
    }
    st[j * 4 + 0] = b1;
    st[j * 4 + 1] = (int)A1;
  }
}

// Vectorized u16 key stream: write decided mask bits, gather cutoff candidates.
__global__ __launch_bounds__(256) void mask_gather_kernel(
    const unsigned short* __restrict__ keys, const int* __restrict__ st,
    float* __restrict__ out, unsigned* __restrict__ ccount,
    int* __restrict__ cidx) {
  int blk = blockIdx.x;              // 40 * 32
  int j = blk >> 5, seg = blk & 31;  // 8192 keys per segment
  int b = j / 5, l = j % 5 + 1;
  int rowg = b * 6 + l;
  unsigned b1 = (unsigned)st[j * 4 + 0];
  const uint4* kp = (const uint4*)(keys + (size_t)j * NPIX + seg * 8192);
  float4* o4 = (float4*)(out + (size_t)rowg * NPIX + seg * 8192);
#pragma unroll
  for (int it = 0; it < 4; ++it) {
    int q = threadIdx.x + it * 256;
    uint4 k4 = kp[q];                // 8 u16 keys
    unsigned w[4] = {k4.x, k4.y, k4.z, k4.w};
    float4 mv[2];
    float* mf = (float*)mv;
#pragma unroll
    for (int e = 0; e < 4; ++e) {
      unsigned lo = (w[e] & 0xFFFFu) >> 4;
      unsigned hi = w[e] >> 20;
      mf[e * 2] = lo > b1 ? 1.f : 0.f;
      mf[e * 2 + 1] = hi > b1 ? 1.f : 0.f;
      if (lo == b1) {
        unsigned s = atomicAdd(&ccount[j], 1u);
        if (s < CAND_CAP) cidx[j * CAND_CAP + s] = seg * 8192 + q * 8 + e * 2;
      }
      if (hi == b1) {
        unsigned s = atomicAdd(&ccount[j], 1u);
        if (s < CAND_CAP) cidx[j * CAND_CAP + s] = seg * 8192 + q * 8 + e * 2 + 1;
      }
    }
    o4[q * 2] = mv[0];
    o4[q * 2 + 1] = mv[1];
  }
}

// Recompute exact f64 values for candidates (bit-identical chain), exact rank
// with (value desc, index asc) tie-break, set top R = K - A1.
__global__ __launch_bounds__(256) void finalize_kernel(
    const float* __restrict__ conf, const float* __restrict__ warp,
    const float* __restrict__ gk, const int* __restrict__ st,
    const unsigned* __restrict__ ccount, const int* __restrict__ cidx,
    float* __restrict__ out) {
  int j = blockIdx.x;
  int b = j / 5, l = j % 5 + 1;
  int rowg = b * 6 + l;
  const float* confr = conf + (size_t)rowg * 4u * NPIX;
  const float* warpr = warp + (size_t)b * NPIX;
  __shared__ double vs[CAND_CAP];    // 32 KB
  __shared__ int ids[CAND_CAP];      // 16 KB
  __shared__ double g[25];
  int tid = threadIdx.x;
  if (tid < 25) g[tid] = (double)gk[tid];
  unsigned A1 = (unsigned)st[j * 4 + 1];
  int R = (int)(KSEL - A1);
  int C = (int)min(ccount[j], (unsigned)CAND_CAP);
  __syncthreads();
  for (int i = tid; i < C; i += 256) {
    int idx = cidx[j * CAND_CAP + i];
    int y = idx >> 9, x = idx & 511;
    double acc = 0.0;
#pragma unroll
    for (int dy = 0; dy < 5; ++dy)
#pragma unroll
      for (int dx = 0; dx < 5; ++dx)
        acc = fma(g[dy * 5 + dx], m_val(confr, warpr, y + dy - 2, x + dx - 2), acc);
    vs[i] = acc;
    ids[i] = idx;
  }
  __syncthreads();
  for (int i = tid; i < C; i += 256) {
    double vi = vs[i];
    int ii = ids[i];
    int rank = 0;
    for (int q = 0; q < C; ++q) {
      double vq = vs[q];
      rank += (vq > vi) || (vq == vi && ids[q] < ii) ? 1 : 0;
    }
    if (rank < R) out[(size_t)rowg * NPIX + ii] = 1.0f;
  }
  if (j == 0 && tid == 0) out[12582912] = 0.5f;  // rate == 0.5 exactly
}

extern "C" void kernel_launch(void* const* d_in, const int* in_sizes, int n_in,
                              void* d_out, int out_size, void* d_ws, size_t ws_size,
                              hipStream_t stream) {
  const float* conf = (const float*)d_in[0];
  const float* warp = (const float*)d_in[1];
  const float* gk   = (const float*)d_in[2];
  float* out = (float*)d_out;
  char* ws = (char*)d_ws;

  unsigned short* keys = (unsigned short*)(ws + OFF_KEY);
  unsigned* h1 = (unsigned*)(ws + OFF_H1);
  int*      st = (int*)(ws + OFF_ST);
  unsigned* cc = (unsigned*)(ws + OFF_CC);
  int*      ci = (int*)(ws + OFF_CI);

  hipMemsetAsync(ws + OFF_H1, 0, (size_t)META_BYTES, stream);

  ego_fill_kernel<<<2048, 256, 0, stream>>>(out);
  compute_kernel<<<NROWSEL * 128, 256, 0, stream>>>(conf, warp, gk, keys, h1);
  scan1_kernel<<<NROWSEL, 256, 0, stream>>>(h1, st);
  mask_gather_kernel<<<NROWSEL * 32, 256, 0, stream>>>(keys, st, out, cc, ci);
  finalize_kernel<<<NROWSEL, 256, 0, stream>>>(conf, warp, gk, st, cc, ci, out);
}

// Round 4
// 149.964 us; speedup vs baseline: 3.4000x; 3.4000x over previous
//
#include <hip/hip_runtime.h>

// confidence_maps: (8,6,4,512,512) f32; warp_masks: (8,1,512,512) f32;
// gauss_kernel: (1,1,5,5) f32.
// Output: mask (48,1,512,512) f32 + rate scalar = 12,582,913 floats.
//
// Validated invariants (rounds 1-3, absmax 0.0):
//  - rate == 0.5 exactly; ego rows (l==0) all-ones, excluded from rate.
//  - max_c(sigmoid) == sigmoid(max_c); f64 pipeline matches np ref ordering.
//  - finalize recompute is bit-identical to compute (same m_val + fma order).
//
// Round-4 changes (round-3 post-mortem: finalize 268 us, latency-bound at
// 1.6% occupancy, C ~ hundreds; compute slowed by 21M global hist-flush
// atomics):
//  - two-level 16-bit selection on the stored u16 keys: 256-bin coarse hist
//    in compute (1 KB LDS, 1.3M flush atomics), then a 256-sub-bin refine
//    pass -> exact 16-bit prefix; cutoff candidates ~50/row.
//  - compute LDS 20.8 KB, launch_bounds(256,5).

#define NROWSEL 40
#define NPIX    262144
#define KSEL    131072u
#define CAND_CAP 2048

// ---- workspace layout (bytes) ----
#define OFF_KEY  0ull                  // 40*262144 u16 = 20,971,520
#define OFF_H1   20971520ull           // 40*256 u32    =     40,960
#define OFF_H2   21012480ull           // 40*256 u32    =     40,960
#define OFF_ST   21053440ull           // 40*4 int      =        640
#define OFF_CC   21054080ull           // 40 u32        =        160
#define OFF_CI   21054240ull           // 40*2048 int   =    327,680
#define META_BYTES 82720ull            // zero H1 + H2 + ST + CC

__device__ __forceinline__ unsigned qkey(double v) {
  double t = v * 4294967296.0;
  t = fmax(t, 0.0);
  t = fmin(t, 4294967295.0);
  return (unsigned)t;
}

// m = sigmoid(max_c conf) * warp, f64. Shared by compute & finalize so the
// recomputation in finalize is BIT-IDENTICAL.
__device__ __forceinline__ double m_val(const float* __restrict__ confr,
                                        const float* __restrict__ warpr,
                                        int gy, int gx) {
  if (gy < 0 || gy >= 512 || gx < 0 || gx >= 512) return 0.0;
  int off = gy * 512 + gx;
  float x0 = confr[off];
  float x1 = confr[NPIX + off];
  float x2 = confr[2 * NPIX + off];
  float x3 = confr[3 * NPIX + off];
  float mx = fmaxf(fmaxf(x0, x1), fmaxf(x2, x3));
  double s = 1.0 / (1.0 + exp(-(double)mx));
  return s * (double)warpr[off];
}

__global__ void ego_fill_kernel(float* __restrict__ out) {
  int i = blockIdx.x * 256 + threadIdx.x;   // 524288 float4 units
  int b = i >> 16;
  int o4 = i & 65535;
  float4* p = (float4*)(out + (size_t)b * 6u * NPIX) + o4;
  *p = make_float4(1.f, 1.f, 1.f, 1.f);
}

// Fused: f64 m halo tile (36x68) in LDS, 25-tap f64 conv (fixed fma chain),
// u16 key store, 256-bin LDS histogram of key bits [31:24].
__global__ __launch_bounds__(256, 5) void compute_kernel(
    const float* __restrict__ conf, const float* __restrict__ warp,
    const float* __restrict__ gk, unsigned short* __restrict__ keys,
    unsigned* __restrict__ hist1) {
  const int blk = blockIdx.x;        // 40 * 128
  const int j = blk >> 7;            // row 0..39
  const int tile = blk & 127;        // 16 (y) x 8 (x) tiles of 32x64
  const int ty0 = (tile >> 3) << 5;
  const int tx0 = (tile & 7) << 6;
  const int b = j / 5;
  const int l = j % 5 + 1;
  const int rowg = b * 6 + l;
  const float* confr = conf + (size_t)rowg * 4u * NPIX;
  const float* warpr = warp + (size_t)b * NPIX;

  __shared__ double mt[36][68];      // 19584 B
  __shared__ double g[25];
  __shared__ unsigned lh[256];       // 1024 B => ~20.8 KB total
  const int tid = threadIdx.x;
  if (tid < 25) g[tid] = (double)gk[tid];
  lh[tid] = 0u;

  for (int i = tid; i < 36 * 68; i += 256) {
    int hy = i / 68, hx = i % 68;
    mt[hy][hx] = m_val(confr, warpr, ty0 + hy - 2, tx0 + hx - 2);
  }
  __syncthreads();

  const int txl = tid & 63;
  const int tyl = tid >> 6;          // 0..3
  unsigned short* keyrow = keys + (size_t)j * NPIX;
  for (int rr = 0; rr < 8; ++rr) {
    int yy = tyl + (rr << 2);        // 0..31
    double acc = 0.0;
#pragma unroll
    for (int dy = 0; dy < 5; ++dy)
#pragma unroll
      for (int dx = 0; dx < 5; ++dx)
        acc = fma(g[dy * 5 + dx], mt[yy + dy][txl + dx], acc);
    unsigned k = qkey(acc);
    keyrow[(ty0 + yy) * 512 + (tx0 + txl)] = (unsigned short)(k >> 16);
    atomicAdd(&lh[k >> 24], 1u);
  }
  __syncthreads();
  if (lh[tid]) atomicAdd(&hist1[j * 256 + tid], lh[tid]);
}

// Coarse level: find bin b1 (descending over 256 bins); A1 = count above.
__global__ void scan1_kernel(const unsigned* __restrict__ hist1,
                             int* __restrict__ st) {
  int j = blockIdx.x;
  const unsigned* h = hist1 + j * 256;
  __shared__ unsigned cs[256];
  int tid = threadIdx.x;
  cs[tid] = h[tid];
  __syncthreads();
  if (tid == 0) {
    unsigned cum = 0; int b1 = 255; unsigned A1 = 0;
    for (int c = 255; c >= 0; --c) {
      if (cum + cs[c] >= KSEL) { b1 = c; A1 = cum; break; }
      cum += cs[c];
    }
    st[j * 4 + 0] = b1;
    st[j * 4 + 1] = (int)A1;
  }
}

// Refine: histogram key bits [7:0] for u16 keys whose high byte == b1.
__global__ __launch_bounds__(256) void hist2_kernel(
    const unsigned short* __restrict__ keys, const int* __restrict__ st,
    unsigned* __restrict__ hist2) {
  int blk = blockIdx.x;              // 40 * 32
  int j = blk >> 5, seg = blk & 31;  // 8192 keys per segment
  unsigned b1 = (unsigned)st[j * 4 + 0];
  const uint4* kp = (const uint4*)(keys + (size_t)j * NPIX + seg * 8192);
  __shared__ unsigned lh[256];
  lh[threadIdx.x] = 0u;
  __syncthreads();
#pragma unroll
  for (int it = 0; it < 4; ++it) {
    uint4 k4 = kp[threadIdx.x + it * 256];
    unsigned w[4] = {k4.x, k4.y, k4.z, k4.w};
#pragma unroll
    for (int e = 0; e < 4; ++e) {
      unsigned lo = w[e] & 0xFFFFu, hi = w[e] >> 16;
      if ((lo >> 8) == b1) atomicAdd(&lh[lo & 255u], 1u);
      if ((hi >> 8) == b1) atomicAdd(&lh[hi & 255u], 1u);
    }
  }
  __syncthreads();
  if (lh[threadIdx.x]) atomicAdd(&hist2[j * 256 + threadIdx.x], lh[threadIdx.x]);
}

// Find sub-bin: pstar = (b1<<8)|b2 (full u16 prefix); A2 = count above pstar.
__global__ void scan2_kernel(const unsigned* __restrict__ hist2,
                             int* __restrict__ st) {
  int j = blockIdx.x;
  const unsigned* h = hist2 + j * 256;
  __shared__ unsigned cs[256];
  int tid = threadIdx.x;
  cs[tid] = h[tid];
  __syncthreads();
  if (tid == 0) {
    unsigned b1 = (unsigned)st[j * 4 + 0];
    unsigned A1 = (unsigned)st[j * 4 + 1];
    unsigned cum = A1; int b2 = 255; unsigned A2 = A1;
    for (int c = 255; c >= 0; --c) {
      if (cum + cs[c] >= KSEL) { b2 = c; A2 = cum; break; }
      cum += cs[c];
    }
    st[j * 4 + 2] = (int)((b1 << 8) | (unsigned)b2);
    st[j * 4 + 3] = (int)A2;
  }
}

// Write decided mask bits from u16 keys; gather cutoff candidates (==pstar).
__global__ __launch_bounds__(256) void mask_gather_kernel(
    const unsigned short* __restrict__ keys, const int* __restrict__ st,
    float* __restrict__ out, unsigned* __restrict__ ccount,
    int* __restrict__ cidx) {
  int blk = blockIdx.x;              // 40 * 32
  int j = blk >> 5, seg = blk & 31;
  int b = j / 5, l = j % 5 + 1;
  int rowg = b * 6 + l;
  unsigned pstar = (unsigned)st[j * 4 + 2];
  const uint4* kp = (const uint4*)(keys + (size_t)j * NPIX + seg * 8192);
  float4* o4 = (float4*)(out + (size_t)rowg * NPIX + seg * 8192);
#pragma unroll
  for (int it = 0; it < 4; ++it) {
    int q = threadIdx.x + it * 256;
    uint4 k4 = kp[q];                // 8 u16 keys
    unsigned w[4] = {k4.x, k4.y, k4.z, k4.w};
    float4 mv[2];
    float* mf = (float*)mv;
#pragma unroll
    for (int e = 0; e < 4; ++e) {
      unsigned lo = w[e] & 0xFFFFu;
      unsigned hi = w[e] >> 16;
      mf[e * 2] = lo > pstar ? 1.f : 0.f;
      mf[e * 2 + 1] = hi > pstar ? 1.f : 0.f;
      if (lo == pstar) {
        unsigned s = atomicAdd(&ccount[j], 1u);
        if (s < CAND_CAP) cidx[j * CAND_CAP + s] = seg * 8192 + q * 8 + e * 2;
      }
      if (hi == pstar) {
        unsigned s = atomicAdd(&ccount[j], 1u);
        if (s < CAND_CAP) cidx[j * CAND_CAP + s] = seg * 8192 + q * 8 + e * 2 + 1;
      }
    }
    o4[q * 2] = mv[0];
    o4[q * 2 + 1] = mv[1];
  }
}

// Recompute exact f64 values for the ~50 candidates (bit-identical chain),
// exact rank with (value desc, index asc) tie-break, set top R = K - A2.
__global__ __launch_bounds__(256) void finalize_kernel(
    const float* __restrict__ conf, const float* __restrict__ warp,
    const float* __restrict__ gk, const int* __restrict__ st,
    const unsigned* __restrict__ ccount, const int* __restrict__ cidx,
    float* __restrict__ out) {
  int j = blockIdx.x;
  int b = j / 5, l = j % 5 + 1;
  int rowg = b * 6 + l;
  const float* confr = conf + (size_t)rowg * 4u * NPIX;
  const float* warpr = warp + (size_t)b * NPIX;
  __shared__ double vs[CAND_CAP];    // 16 KB
  __shared__ int ids[CAND_CAP];      //  8 KB
  __shared__ double g[25];
  int tid = threadIdx.x;
  if (tid < 25) g[tid] = (double)gk[tid];
  unsigned A2 = (unsigned)st[j * 4 + 3];
  int R = (int)(KSEL - A2);
  int C = (int)min(ccount[j], (unsigned)CAND_CAP);
  __syncthreads();
  for (int i = tid; i < C; i += 256) {
    int idx = cidx[j * CAND_CAP + i];
    int y = idx >> 9, x = idx & 511;
    double acc = 0.0;
#pragma unroll
    for (int dy = 0; dy < 5; ++dy)
#pragma unroll
      for (int dx = 0; dx < 5; ++dx)
        acc = fma(g[dy * 5 + dx], m_val(confr, warpr, y + dy - 2, x + dx - 2), acc);
    vs[i] = acc;
    ids[i] = idx;
  }
  __syncthreads();
  for (int i = tid; i < C; i += 256) {
    double vi = vs[i];
    int ii = ids[i];
    int rank = 0;
    for (int q = 0; q < C; ++q) {
      double vq = vs[q];
      rank += (vq > vi) || (vq == vi && ids[q] < ii) ? 1 : 0;
    }
    if (rank < R) out[(size_t)rowg * NPIX + ii] = 1.0f;
  }
  if (j == 0 && tid == 0) out[12582912] = 0.5f;  // rate == 0.5 exactly
}

extern "C" void kernel_launch(void* const* d_in, const int* in_sizes, int n_in,
                              void* d_out, int out_size, void* d_ws, size_t ws_size,
                              hipStream_t stream) {
  const float* conf = (const float*)d_in[0];
  const float* warp = (const float*)d_in[1];
  const float* gk   = (const float*)d_in[2];
  float* out = (float*)d_out;
  char* ws = (char*)d_ws;

  unsigned short* keys = (unsigned short*)(ws + OFF_KEY);
  unsigned* h1 = (unsigned*)(ws + OFF_H1);
  unsigned* h2 = (unsigned*)(ws + OFF_H2);
  int*      st = (int*)(ws + OFF_ST);
  unsigned* cc = (unsigned*)(ws + OFF_CC);
  int*      ci = (int*)(ws + OFF_CI);

  hipMemsetAsync(ws + OFF_H1, 0, (size_t)META_BYTES, stream);

  ego_fill_kernel<<<2048, 256, 0, stream>>>(out);
  compute_kernel<<<NROWSEL * 128, 256, 0, stream>>>(conf, warp, gk, keys, h1);
  scan1_kernel<<<NROWSEL, 256, 0, stream>>>(h1, st);
  hist2_kernel<<<NROWSEL * 32, 256, 0, stream>>>(keys, st, h2);
  scan2_kernel<<<NROWSEL, 256, 0, stream>>>(h2, st);
  mask_gather_kernel<<<NROWSEL * 32, 256, 0, stream>>>(keys, st, out, cc, ci);
  finalize_kernel<<<NROWSEL, 256, 0, stream>>>(conf, warp, gk, st, cc, ci, out);
}